// Round 7
// baseline (150.557 us; speedup 1.0000x reference)
//
#include <hip/hip_runtime.h>
#include <hip/hip_bf16.h>

#define IMG 256
#define TS 20

typedef unsigned short u16;
typedef __bf16 bf16x8 __attribute__((ext_vector_type(8)));
typedef float f32x4 __attribute__((ext_vector_type(4)));
typedef unsigned short ushort8 __attribute__((ext_vector_type(8)));

__device__ __forceinline__ float cc1f(float x) {
    const float A = -0.75f;
    return ((A + 2.0f) * x - (A + 3.0f)) * x * x + 1.0f;
}
__device__ __forceinline__ float cc2f(float x) {
    const float A = -0.75f;
    return ((A * x - 5.0f * A) * x + 8.0f * A) * x - 4.0f * A;
}

// fp32 -> bf16 round-to-nearest-even, bit form
__device__ __forceinline__ u16 f2bf(float f) {
    unsigned u = __float_as_uint(f);
    u = u + 0x7fffu + ((u >> 16) & 1u);
    return (u16)(u >> 16);
}

// ---------------------------------------------------------------------------
// build_P2: P_0 = I; P_{i+1} = (N·B)_i · P_i  (row-gather, 4 nnz/row).
// Column-sliced: 32 blocks × 8 columns; 256 threads = one thread per row.
// (verified R4/R5, ~4 µs)
// ---------------------------------------------------------------------------
#define BPC 8
#define BPS 12
__global__ __launch_bounds__(256) void build_P2(u16* __restrict__ Pbf) {
    __shared__ __align__(16) float buf[2][IMG][BPS];
    const int col0 = blockIdx.x * BPC;
    const int o = threadIdx.x;

    f32x4 n0 = (f32x4){0.f, 0.f, 0.f, 0.f};
    f32x4 n1 = (f32x4){0.f, 0.f, 0.f, 0.f};
    if (o >= col0 && o < col0 + 4) n0[o - col0] = 1.0f;
    if (o >= col0 + 4 && o < col0 + 8) n1[o - col0 - 4] = 1.0f;
    *(f32x4*)&buf[0][o][0] = n0;
    *(f32x4*)&buf[0][o][4] = n1;
    {
        ushort8 pk;
#pragma unroll
        for (int c = 0; c < 4; ++c) pk[c] = f2bf(n0[c]);
#pragma unroll
        for (int c = 0; c < 4; ++c) pk[4 + c] = f2bf(n1[c]);
        *(ushort8*)(Pbf + (size_t)o * IMG + col0) = pk;
    }

    int cur = 0;
#pragma unroll
    for (int i = 0; i < TS - 1; ++i) {
        const int s = IMG - i;
        float xs = (o + 0.5f) * (float)s * (1.0f / 256.0f);
        int j = (int)xs;
        if (j > s - 1) j = s - 1;
        float x = (j + 0.5f) * (256.0f / (float)s) - 0.5f;
        float fl = floorf(x);
        int i0 = (int)fl;
        float tt = x - fl;
        float w[4] = {cc2f(tt + 1.0f), cc1f(tt), cc1f(1.0f - tt), cc2f(2.0f - tt)};
        int c[4];
#pragma unroll
        for (int k = 0; k < 4; ++k) c[k] = min(max(i0 - 1 + k, 0), IMG - 1);

        __syncthreads();
        f32x4 a0 = (f32x4){0.f, 0.f, 0.f, 0.f};
        f32x4 a1 = (f32x4){0.f, 0.f, 0.f, 0.f};
#pragma unroll
        for (int k = 0; k < 4; ++k) {
            const float wk = w[k];
            a0 += wk * *(const f32x4*)&buf[cur][c[k]][0];
            a1 += wk * *(const f32x4*)&buf[cur][c[k]][4];
        }
        const int nxt = cur ^ 1;
        *(f32x4*)&buf[nxt][o][0] = a0;
        *(f32x4*)&buf[nxt][o][4] = a1;

        ushort8 pk;
#pragma unroll
        for (int cc = 0; cc < 4; ++cc) pk[cc] = f2bf(a0[cc]);
#pragma unroll
        for (int cc = 0; cc < 4; ++cc) pk[4 + cc] = f2bf(a1[cc]);
        *(ushort8*)(Pbf + ((size_t)(i + 1) * IMG + o) * IMG + col0) = pk;
        cur = nxt;
    }
}

// ---------------------------------------------------------------------------
// fused_img: block (bc, q) computes out[:, q*64 : q*64+64] for image bc.
//   phase1: zslab[p][h] = sum_w P[p0+p][w] * X[h][w]   (p in [0,64), Z in LDS)
//   phase2: out[o][p0+p] = sum_h P[o][h] * zslab[p][h] (B from LDS, no staging)
// 4 waves, 256 threads. LDS: zslab 32 KB + stage 40 KB = 72 KB -> 2 blocks/CU.
// Z never touches global memory. grid(192,4): image quarters on one XCD.
// All MFMA / swizzle idioms identical to the R1-verified gemm_px.
// ---------------------------------------------------------------------------
__global__ __launch_bounds__(256) void fused_img(const u16* __restrict__ Pbf,
                                                 const float* __restrict__ X,
                                                 float* __restrict__ out,
                                                 const int* __restrict__ tarr) {
    __shared__ __align__(16) u16 zslab[64 * IMG];        // 32 KB, [p][h] swizzled
    __shared__ __align__(16) u16 stage[(IMG + 64) * 64]; // 40 KB

    const int bc = blockIdx.x;
    const int p0 = blockIdx.y * 64;
    const int tsel = tarr[bc / 3];
    const u16* __restrict__ P = Pbf + (size_t)tsel * IMG * IMG;
    const float* __restrict__ Xb = X + (size_t)bc * IMG * IMG;
    float* __restrict__ outb = out + (size_t)bc * IMG * IMG;

    const int tid = threadIdx.x;
    const int lane = tid & 63;
    const int wave = tid >> 6;
    const int l15 = lane & 15;
    const int lhi = lane >> 4;
    const int row4 = lhi * 4;

    u16* stB = stage;               // 256*64 u16 (phase1 X-tile / phase2 P-tile)
    u16* stA = stage + IMG * 64;    // 64*64 u16 (phase1 P-tile)

    // ================= phase 1: Z slab =================
    const int wn1 = wave * 64;  // h-range of this wave
    f32x4 acc[4][4];
#pragma unroll
    for (int i = 0; i < 4; ++i)
#pragma unroll
        for (int j = 0; j < 4; ++j) acc[i][j] = (f32x4){0.f, 0.f, 0.f, 0.f};

    for (int kt = 0; kt < 4; ++kt) {
        __syncthreads();
        // stage A: P rows [p0, p0+64) x k-cols [kt*64, +64): 512 chunks / 256 thr
#pragma unroll
        for (int s = 0; s < 2; ++s) {
            const int id = s * 256 + tid;
            const int row = id >> 3;
            const int kb = id & 7;
            const uint4 av = *(const uint4*)(P + (size_t)(p0 + row) * IMG + kt * 64 + kb * 8);
            *(uint4*)(stA + row * 64 + ((kb ^ (row & 7)) * 8)) = av;
        }
        // stage B: X rows [0,256) x same k-cols, fp32 -> bf16: 2048 chunks
#pragma unroll
        for (int s = 0; s < 8; ++s) {
            const int id = s * 256 + tid;
            const int row = id >> 3;
            const int kb = id & 7;
            const float* xs = Xb + (size_t)row * IMG + kt * 64 + kb * 8;
            const float4 v0 = *(const float4*)(xs);
            const float4 v1 = *(const float4*)(xs + 4);
            ushort8 pk;
            pk[0] = f2bf(v0.x); pk[1] = f2bf(v0.y); pk[2] = f2bf(v0.z); pk[3] = f2bf(v0.w);
            pk[4] = f2bf(v1.x); pk[5] = f2bf(v1.y); pk[6] = f2bf(v1.z); pk[7] = f2bf(v1.w);
            *(ushort8*)(stB + row * 64 + ((kb ^ (row & 7)) * 8)) = pk;
        }
        __syncthreads();
#pragma unroll
        for (int kk = 0; kk < 2; ++kk) {
            const int ck = kk * 4 + lhi;
            bf16x8 afrag[4], bfrag[4];
#pragma unroll
            for (int mi = 0; mi < 4; ++mi) {
                const int r = mi * 16 + l15;  // p (0..63)
                afrag[mi] = *(const bf16x8*)(stA + r * 64 + ((ck ^ (r & 7)) * 8));
            }
#pragma unroll
            for (int nj = 0; nj < 4; ++nj) {
                const int r = wn1 + nj * 16 + l15;  // h
                bfrag[nj] = *(const bf16x8*)(stB + r * 64 + ((ck ^ (r & 7)) * 8));
            }
#pragma unroll
            for (int mi = 0; mi < 4; ++mi)
#pragma unroll
                for (int nj = 0; nj < 4; ++nj)
                    acc[mi][nj] = __builtin_amdgcn_mfma_f32_16x16x32_bf16(
                        afrag[mi], bfrag[nj], acc[mi][nj], 0, 0, 0);
        }
    }

    // write Z slab -> LDS [p][h], 16B-chunk XOR swizzle on h
#pragma unroll
    for (int mi = 0; mi < 4; ++mi)
#pragma unroll
        for (int nj = 0; nj < 4; ++nj)
#pragma unroll
            for (int r = 0; r < 4; ++r) {
                const int p = mi * 16 + row4 + r;       // 0..63
                const int h = wn1 + nj * 16 + l15;      // 0..255
                zslab[p * IMG + (((h >> 3) ^ (p & 7)) * 8) + (h & 7)] =
                    f2bf(acc[mi][nj][r]);
            }

    // ================= phase 2: out columns =================
    const int wm2 = wave * 64;  // o-range of this wave
    f32x4 acc2[4][4];
#pragma unroll
    for (int i = 0; i < 4; ++i)
#pragma unroll
        for (int j = 0; j < 4; ++j) acc2[i][j] = (f32x4){0.f, 0.f, 0.f, 0.f};

    for (int kt = 0; kt < 4; ++kt) {
        __syncthreads();  // stage reads done (prev iter / phase1) + zslab visible
        // stage A: P rows [0,256) x k-cols [kt*64, +64): 2048 chunks
#pragma unroll
        for (int s = 0; s < 8; ++s) {
            const int id = s * 256 + tid;
            const int row = id >> 3;
            const int kb = id & 7;
            const uint4 av = *(const uint4*)(P + (size_t)row * IMG + kt * 64 + kb * 8);
            *(uint4*)(stB + row * 64 + ((kb ^ (row & 7)) * 8)) = av;
        }
        __syncthreads();
#pragma unroll
        for (int kk = 0; kk < 2; ++kk) {
            const int ck = kk * 4 + lhi;            // chunk within kt tile
            const int ck2 = kt * 8 + ck;            // global h-chunk (0..31)
            bf16x8 afrag[4], bfrag[4];
#pragma unroll
            for (int mi = 0; mi < 4; ++mi) {
                const int r = wm2 + mi * 16 + l15;  // o
                afrag[mi] = *(const bf16x8*)(stB + r * 64 + ((ck ^ (r & 7)) * 8));
            }
#pragma unroll
            for (int nj = 0; nj < 4; ++nj) {
                const int r = nj * 16 + l15;        // p (0..63)
                bfrag[nj] = *(const bf16x8*)(zslab + r * IMG + ((ck2 ^ (r & 7)) * 8));
            }
#pragma unroll
            for (int mi = 0; mi < 4; ++mi)
#pragma unroll
                for (int nj = 0; nj < 4; ++nj)
                    acc2[mi][nj] = __builtin_amdgcn_mfma_f32_16x16x32_bf16(
                        afrag[mi], bfrag[nj], acc2[mi][nj], 0, 0, 0);
        }
    }

    // store out fp32: o = m-side, p = n-side
#pragma unroll
    for (int mi = 0; mi < 4; ++mi)
#pragma unroll
        for (int nj = 0; nj < 4; ++nj)
#pragma unroll
            for (int r = 0; r < 4; ++r) {
                const int o = wm2 + mi * 16 + row4 + r;
                const int p = p0 + nj * 16 + l15;
                outb[(size_t)o * IMG + p] = acc2[mi][nj][r];
            }
}

// ---------------------------------------------------------------------------
extern "C" void kernel_launch(void* const* d_in, const int* in_sizes, int n_in,
                              void* d_out, int out_size, void* d_ws, size_t ws_size,
                              hipStream_t stream) {
    const float* x0 = (const float*)d_in[0];
    const int* t = (const int*)d_in[1];
    float* out = (float*)d_out;

    u16* Pbf = (u16*)d_ws;  // 20*256*256 bf16 = 2.62 MB

    hipLaunchKernelGGL(build_P2, dim3(IMG / BPC), dim3(IMG), 0, stream, Pbf);
    hipLaunchKernelGGL(fused_img, dim3(192, 4), dim3(256), 0, stream,
                       Pbf, x0, out, t);
}